// Round 8
// baseline (589.155 us; speedup 1.0000x reference)
//
#include <hip/hip_runtime.h>
#include <hip/hip_bf16.h>

#define N_NODES 50000
#define DIM 128
#define N_GRAPHS 64
#define E_RAW 800000
#define E_TOT 850000
#define NSLOT 1000000   // E_TOT + 3*N_NODES: exact upper bound on padded slots
#define E_CAP 1200000
#define NEG_SLOPE 0.2f
#define PAD_SENT 0xFFFF0000u   // src field = 0 (safe gather), dst field = 0xFFFF (pad)

typedef unsigned int uint;
typedef unsigned short ushort;
typedef float v2f __attribute__((ext_vector_type(2)));
typedef short bf16x8 __attribute__((ext_vector_type(8)));
typedef float f32x4 __attribute__((ext_vector_type(4)));

// Column permutation pi (storage position -> logical feature), fixed by the
// MFMA C/D fragment layout: pi(p) = (p>>3) + 32*((p>>1)&3) + 16*(p&1)
__device__ __forceinline__ int pi_pos(int p) {
    return (p >> 3) + 32 * ((p >> 1) & 3) + 16 * (p & 1);
}

__device__ __forceinline__ ushort f2bf(float f) {
    uint u = __float_as_uint(f);
    u += 0x7fffu + ((u >> 16) & 1u);      // RNE
    return (ushort)(u >> 16);
}

// ---------- init: counters + pooled only ----------
__global__ void init_kernel(int* deg, int* fillc, float* pooled) {
    int i = blockIdx.x * blockDim.x + threadIdx.x;
    if (i < N_NODES) { deg[i] = 0; fillc[i] = 0; }
    if (i < N_GRAPHS * DIM) pooled[i] = 0.f;
}

// ---------- fill csr[0..NSLOT) with pad sentinel ----------
__global__ void csr_init_kernel(uint* __restrict__ csr) {
    int i = blockIdx.x * blockDim.x + threadIdx.x;
    if (i < NSLOT / 4) ((uint4*)csr)[i] = make_uint4(PAD_SENT, PAD_SENT, PAD_SENT, PAD_SENT);
}

// ---------- layer-0 input fp32 -> bf16 (natural order) ----------
__global__ void x2bf_kernel(const float* __restrict__ x, ushort* __restrict__ xb) {
    int i = blockIdx.x * blockDim.x + threadIdx.x;
    if (i >= N_NODES * DIM / 4) return;
    float4 v = ((const float4*)x)[i];
    ushort4 o;
    o.x = f2bf(v.x); o.y = f2bf(v.y); o.z = f2bf(v.z); o.w = f2bf(v.w);
    ((ushort4*)xb)[i] = o;
}

// ---------- pack W into per-lane MFMA B-fragment layout (bf16) ----------
__global__ void wprep_kernel(const float* __restrict__ Ws, ushort* __restrict__ Wfrag) {
    int t = blockIdx.x * blockDim.x + threadIdx.x;
    if (t >= 3 * 32 * 64) return;
    int l = t >> 11;
    int rem = t & 2047;
    int chunk = rem >> 6, lane = rem & 63;
    int ks = chunk >> 3, nt = chunk & 7;
    int cc = lane & 15, gg = lane >> 4;
    const float* W = Ws + (size_t)l * DIM * DIM;
    ushort o[8];
#pragma unroll
    for (int j = 0; j < 8; ++j) {
        int kp = ks * 32 + gg * 8 + j;
        int kl = (l == 0) ? kp : pi_pos(kp);
        o[j] = f2bf(W[kl * DIM + nt * 16 + cc]);
    }
#pragma unroll
    for (int j = 0; j < 8; ++j) Wfrag[(size_t)t * 8 + j] = o[j];
}

// ---------- CSR build (dst-sorted, segments padded to multiple of 4) ----------
__global__ void count_kernel(const int* __restrict__ ei, int* __restrict__ deg) {
    int e = blockIdx.x * blockDim.x + threadIdx.x;
    if (e >= E_TOT) return;
    int dst = (e < E_RAW) ? ei[E_RAW + e] : (e - E_RAW);
    atomicAdd(&deg[dst], 1);
}

__global__ void scan1_kernel(const int* __restrict__ deg, int* __restrict__ excl,
                             int* __restrict__ blksum, int n) {
    __shared__ int lds[256];
    int t = threadIdx.x;
    int i = blockIdx.x * 256 + t;
    int v = (i < n) ? ((deg[i] + 3) & ~3) : 0;   // pad degree to multiple of 4
    lds[t] = v;
    __syncthreads();
    int incl = v;
    for (int off = 1; off < 256; off <<= 1) {
        int y = (t >= off) ? lds[t - off] : 0;
        __syncthreads();
        incl += y;
        lds[t] = incl;
        __syncthreads();
    }
    if (i < n) excl[i] = incl - v;
    if (t == 255) blksum[blockIdx.x] = incl;
}

__global__ void scan2_kernel(int* __restrict__ blksum, int* __restrict__ row_ptr, int nblk) {
    __shared__ int lds[256];
    int t = threadIdx.x;
    int v = (t < nblk) ? blksum[t] : 0;
    lds[t] = v;
    __syncthreads();
    int incl = v;
    for (int off = 1; off < 256; off <<= 1) {
        int y = (t >= off) ? lds[t - off] : 0;
        __syncthreads();
        incl += y;
        lds[t] = incl;
        __syncthreads();
    }
    if (t < nblk) blksum[t] = incl - v;
    if (t == nblk - 1) row_ptr[N_NODES] = incl;
}

__global__ void scan3_kernel(int* __restrict__ row_ptr, const int* __restrict__ blksum, int n) {
    int i = blockIdx.x * blockDim.x + threadIdx.x;
    if (i < n) row_ptr[i] += blksum[i >> 8];
}

// packed entry: src | (dst<<16). N_NODES < 65536 so both fit.
__global__ void fill_kernel(const int* __restrict__ ei, const int* __restrict__ row_ptr,
                            int* __restrict__ fillc, uint* __restrict__ csr) {
    int e = blockIdx.x * blockDim.x + threadIdx.x;
    if (e >= E_TOT) return;
    int src, dst;
    if (e < E_RAW) { src = ei[e]; dst = ei[E_RAW + e]; }
    else           { src = dst = e - E_RAW; }
    int slot = row_ptr[dst] + atomicAdd(&fillc[dst], 1);
    csr[slot] = (uint)src | ((uint)dst << 16);
}

// ---------- MFMA GEMM + fused attention dots; H packed fp8 e4m3 (pi order) ----
__global__ __launch_bounds__(256) void gemm_mfma_kernel(
    const ushort* __restrict__ Xb, const ushort* __restrict__ Wfrag,
    const float* __restrict__ asrc, const float* __restrict__ adst,
    uint* __restrict__ Hb, float* __restrict__ s1, float* __restrict__ s2, int nrows) {
    int wv = threadIdx.x >> 6;
    int lane = threadIdx.x & 63;
    int c = lane & 15, g = lane >> 4;
    int row0 = blockIdx.x * 64 + wv * 16;

    int arow = row0 + c;
    if (arow >= nrows) arow = nrows - 1;           // tail clamp (writes guarded)
    const ushort* xrow = Xb + (size_t)arow * DIM;

    f32x4 acc[8];
#pragma unroll
    for (int nt = 0; nt < 8; ++nt) acc[nt] = (f32x4)(0.f);

#pragma unroll
    for (int ks = 0; ks < 4; ++ks) {
        bf16x8 afrag = *(const bf16x8*)(xrow + ks * 32 + g * 8);
#pragma unroll
        for (int nt = 0; nt < 8; ++nt) {
            bf16x8 bfrag = *(const bf16x8*)(Wfrag + ((size_t)(ks * 8 + nt) * 64 + lane) * 8);
            acc[nt] = __builtin_amdgcn_mfma_f32_16x16x32_bf16(afrag, bfrag, acc[nt], 0, 0, 0);
        }
    }

    float a1[8], a2[8];
#pragma unroll
    for (int nt = 0; nt < 8; ++nt) { a1[nt] = asrc[c + 16 * nt]; a2[nt] = adst[c + 16 * nt]; }

#pragma unroll
    for (int r = 0; r < 4; ++r) {
        int outrow = row0 + g * 4 + r;
        bool valid = outrow < nrows;
        if (valid) {
            int w0 = __builtin_amdgcn_cvt_pk_fp8_f32(acc[0][r], acc[1][r], 0, false);
            w0     = __builtin_amdgcn_cvt_pk_fp8_f32(acc[2][r], acc[3][r], w0, true);
            int w1 = __builtin_amdgcn_cvt_pk_fp8_f32(acc[4][r], acc[5][r], 0, false);
            w1     = __builtin_amdgcn_cvt_pk_fp8_f32(acc[6][r], acc[7][r], w1, true);
            *(uint2*)&Hb[(size_t)outrow * 32 + c * 2] = make_uint2((uint)w0, (uint)w1);
        }
        float p1 = 0.f, p2 = 0.f;
#pragma unroll
        for (int nt = 0; nt < 8; ++nt) {
            p1 = fmaf(acc[nt][r], a1[nt], p1);
            p2 = fmaf(acc[nt][r], a2[nt], p2);
        }
#pragma unroll
        for (int m = 1; m < 16; m <<= 1) { p1 += __shfl_xor(p1, m); p2 += __shfl_xor(p2, m); }
        if (c == 0 && valid) { s1[outrow] = p1; s2[outrow] = p2; }
    }
}

// ---------- per-edge attention weight, fused into the csr word ----------
// reads csr (src|dst<<16); writes cw = src | bf16(exp(leaky(s1+s2)))<<16.
// pad slots (dst==0xFFFF) -> cw = 0 (src 0, weight +0.0f): safe gather, no-op.
__global__ __launch_bounds__(256) void ew_kernel(
    const uint* __restrict__ csr, const float* __restrict__ s1,
    const float* __restrict__ s2, uint* __restrict__ cw) {
    int i = blockIdx.x * blockDim.x + threadIdx.x;
    if (i >= NSLOT / 4) return;
    uint4 e = ((const uint4*)csr)[i];
    uint ev[4] = {e.x, e.y, e.z, e.w};
    uint ov[4];
#pragma unroll
    for (int j = 0; j < 4; ++j) {
        uint dv = ev[j] >> 16;
        uint sv = ev[j] & 0xFFFFu;
        uint out = 0u;
        if (dv != 0xFFFFu) {
            float al = s1[sv] + s2[dv];
            al = fmaxf(al, NEG_SLOPE * al);     // leaky-relu
            float wv = __expf(al);
            out = sv | ((uint)f2bf(wv) << 16);
        }
        ov[j] = out;
    }
    ((uint4*)cw)[i] = make_uint4(ov[0], ov[1], ov[2], ov[3]);
}

// ---------- weighted gather-aggregate: NODE-PER-16-LANE-GROUP ----------
// Each 16-lane group owns a node and walks ALL its edges, 4 per iteration
// (one broadcast uint4 cw load + 4 independent dwordx2 gathers). Each lane
// accumulates its own 8 features -> NO cross-lane butterfly (ws is group-
// uniform by construction). Output: one contiguous 16 B/lane uint4 store
// (8 bf16) -> fixes the 4x write amplification of strided ushort2 stores.
// 4 groups/wave x 2 nodes each = 8 nodes/wave; 16 gathers in flight.
// NO readfirstlane, NO runtime-indexed locals (round-3 LDS-demotion trap).
__global__ __launch_bounds__(256) void agg_kernel(
    const uint2* __restrict__ Hb2, const uint* __restrict__ cw,
    const int* __restrict__ row_ptr, const float* __restrict__ bias,
    uint4* __restrict__ Xout4, const int* __restrict__ batch,
    float* __restrict__ pooled, int pool_flag, int ngroups) {
    int gw = (blockIdx.x * blockDim.x + threadIdx.x) >> 6;
    int lane = threadIdx.x & 63;
    if (gw >= ngroups) return;
    int node0 = gw * 8;
    int ql = lane & 15;         // uint2 (8-feature) index within fp8 row
    int grp = lane >> 4;        // 0..3: which pair of nodes this group owns

    int4 rpa = *(const int4*)&row_ptr[node0];
    int4 rpb = *(const int4*)&row_ptr[node0 + 4];
    int rp8 = row_ptr[node0 + 8];

    // group's two segments: node A = node0+2*grp, node B = node A+1
    int begA = (grp == 0) ? rpa.x : (grp == 1) ? rpa.z : (grp == 2) ? rpb.x : rpb.z;
    int midA = (grp == 0) ? rpa.y : (grp == 1) ? rpa.w : (grp == 2) ? rpb.y : rpb.w;
    int endB = (grp == 0) ? rpa.z : (grp == 1) ? rpb.x : (grp == 2) ? rpb.z : rp8;
    int nodeA = node0 + 2 * grp;

    // bias for this lane's 8 storage positions (pi gather, 512 B table)
    float b0 = bias[pi_pos(8 * ql + 0)], b1 = bias[pi_pos(8 * ql + 1)];
    float b2 = bias[pi_pos(8 * ql + 2)], b3 = bias[pi_pos(8 * ql + 3)];
    float b4 = bias[pi_pos(8 * ql + 4)], b5 = bias[pi_pos(8 * ql + 5)];
    float b6 = bias[pi_pos(8 * ql + 6)], b7 = bias[pi_pos(8 * ql + 7)];

    int bkA = 0, bkB = 0;
    if (pool_flag) {
        int4 bqa = *(const int4*)&batch[node0];
        int4 bqb = *(const int4*)&batch[node0 + 4];
        bkA = (grp == 0) ? bqa.x : (grp == 1) ? bqa.z : (grp == 2) ? bqb.x : bqb.z;
        bkB = (grp == 0) ? bqa.y : (grp == 1) ? bqa.w : (grp == 2) ? bqb.y : bqb.w;
    }

    auto seg = [&](int beg, int end, int bk, int node) {
        float a0 = 0.f, a1 = 0.f, a2 = 0.f, a3 = 0.f;
        float a4 = 0.f, a5 = 0.f, a6 = 0.f, a7 = 0.f, ws = 0.f;

        for (int s = beg; s < end; s += 4) {
            uint4 c = *(const uint4*)&cw[s];    // broadcast within group

            // 4 independent gathers in flight per group (16 per wave)
            uint2 h0 = Hb2[(c.x & 0xFFFFu) * 16u + (uint)ql];
            uint2 h1 = Hb2[(c.y & 0xFFFFu) * 16u + (uint)ql];
            uint2 h2 = Hb2[(c.z & 0xFFFFu) * 16u + (uint)ql];
            uint2 h3 = Hb2[(c.w & 0xFFFFu) * 16u + (uint)ql];
            float w0 = __uint_as_float(c.x & 0xFFFF0000u);
            float w1 = __uint_as_float(c.y & 0xFFFF0000u);
            float w2 = __uint_as_float(c.z & 0xFFFF0000u);
            float w3 = __uint_as_float(c.w & 0xFFFF0000u);

            v2f f;
            f = __builtin_amdgcn_cvt_pk_f32_fp8((int)h0.x, false); a0 = fmaf(w0, f.x, a0); a1 = fmaf(w0, f.y, a1);
            f = __builtin_amdgcn_cvt_pk_f32_fp8((int)h0.x, true);  a2 = fmaf(w0, f.x, a2); a3 = fmaf(w0, f.y, a3);
            f = __builtin_amdgcn_cvt_pk_f32_fp8((int)h0.y, false); a4 = fmaf(w0, f.x, a4); a5 = fmaf(w0, f.y, a5);
            f = __builtin_amdgcn_cvt_pk_f32_fp8((int)h0.y, true);  a6 = fmaf(w0, f.x, a6); a7 = fmaf(w0, f.y, a7);
            f = __builtin_amdgcn_cvt_pk_f32_fp8((int)h1.x, false); a0 = fmaf(w1, f.x, a0); a1 = fmaf(w1, f.y, a1);
            f = __builtin_amdgcn_cvt_pk_f32_fp8((int)h1.x, true);  a2 = fmaf(w1, f.x, a2); a3 = fmaf(w1, f.y, a3);
            f = __builtin_amdgcn_cvt_pk_f32_fp8((int)h1.y, false); a4 = fmaf(w1, f.x, a4); a5 = fmaf(w1, f.y, a5);
            f = __builtin_amdgcn_cvt_pk_f32_fp8((int)h1.y, true);  a6 = fmaf(w1, f.x, a6); a7 = fmaf(w1, f.y, a7);
            f = __builtin_amdgcn_cvt_pk_f32_fp8((int)h2.x, false); a0 = fmaf(w2, f.x, a0); a1 = fmaf(w2, f.y, a1);
            f = __builtin_amdgcn_cvt_pk_f32_fp8((int)h2.x, true);  a2 = fmaf(w2, f.x, a2); a3 = fmaf(w2, f.y, a3);
            f = __builtin_amdgcn_cvt_pk_f32_fp8((int)h2.y, false); a4 = fmaf(w2, f.x, a4); a5 = fmaf(w2, f.y, a5);
            f = __builtin_amdgcn_cvt_pk_f32_fp8((int)h2.y, true);  a6 = fmaf(w2, f.x, a6); a7 = fmaf(w2, f.y, a7);
            f = __builtin_amdgcn_cvt_pk_f32_fp8((int)h3.x, false); a0 = fmaf(w3, f.x, a0); a1 = fmaf(w3, f.y, a1);
            f = __builtin_amdgcn_cvt_pk_f32_fp8((int)h3.x, true);  a2 = fmaf(w3, f.x, a2); a3 = fmaf(w3, f.y, a3);
            f = __builtin_amdgcn_cvt_pk_f32_fp8((int)h3.y, false); a4 = fmaf(w3, f.x, a4); a5 = fmaf(w3, f.y, a5);
            f = __builtin_amdgcn_cvt_pk_f32_fp8((int)h3.y, true);  a6 = fmaf(w3, f.x, a6); a7 = fmaf(w3, f.y, a7);
            ws += (w0 + w1) + (w2 + w3);
        }

        // ws is identical across the group's 16 lanes -> no reduce needed
        float inv = 1.f / (ws + 1e-16f);
        float v0 = fmaxf(fmaf(a0, inv, b0), 0.f);
        float v1 = fmaxf(fmaf(a1, inv, b1), 0.f);
        float v2 = fmaxf(fmaf(a2, inv, b2), 0.f);
        float v3 = fmaxf(fmaf(a3, inv, b3), 0.f);
        float v4 = fmaxf(fmaf(a4, inv, b4), 0.f);
        float v5 = fmaxf(fmaf(a5, inv, b5), 0.f);
        float v6 = fmaxf(fmaf(a6, inv, b6), 0.f);
        float v7 = fmaxf(fmaf(a7, inv, b7), 0.f);

        if (pool_flag) {
            atomicAdd(&pooled[bk * DIM + 8 * ql + 0], v0);
            atomicAdd(&pooled[bk * DIM + 8 * ql + 1], v1);
            atomicAdd(&pooled[bk * DIM + 8 * ql + 2], v2);
            atomicAdd(&pooled[bk * DIM + 8 * ql + 3], v3);
            atomicAdd(&pooled[bk * DIM + 8 * ql + 4], v4);
            atomicAdd(&pooled[bk * DIM + 8 * ql + 5], v5);
            atomicAdd(&pooled[bk * DIM + 8 * ql + 6], v6);
            atomicAdd(&pooled[bk * DIM + 8 * ql + 7], v7);
        } else {
            uint4 o;
            o.x = (uint)f2bf(v0) | ((uint)f2bf(v1) << 16);
            o.y = (uint)f2bf(v2) | ((uint)f2bf(v3) << 16);
            o.z = (uint)f2bf(v4) | ((uint)f2bf(v5) << 16);
            o.w = (uint)f2bf(v6) | ((uint)f2bf(v7) << 16);
            Xout4[(size_t)node * 16 + ql] = o;   // 16 B/lane, contiguous
        }
    };

    seg(begA, midA, bkA, nodeA);
    seg(midA, endB, bkB, nodeA + 1);
}

__global__ void final_kernel(const float* __restrict__ pooled, const float* __restrict__ Wf,
                             const float* __restrict__ bf, float* __restrict__ y) {
    int wid = (blockIdx.x * blockDim.x + threadIdx.x) >> 6;
    int lane = threadIdx.x & 63;
    if (wid >= N_GRAPHS) return;
    float2 p = *(const float2*)&pooled[wid * DIM + 2 * lane];
    int cc = lane >> 2, ii = lane & 3;
    float wx = Wf[cc + 32 * ii];
    float wy = Wf[cc + 32 * ii + 16];
    float v = p.x * wx + p.y * wy;
    for (int off = 32; off; off >>= 1) v += __shfl_down(v, off);
    if (lane == 0) y[wid] = v + bf[0];
}

extern "C" void kernel_launch(void* const* d_in, const int* in_sizes, int n_in,
                              void* d_out, int out_size, void* d_ws, size_t ws_size,
                              hipStream_t stream) {
    const float* x       = (const float*)d_in[0];
    const int*   ei      = (const int*)d_in[1];
    const int*   batch   = (const int*)d_in[2];
    const float* Ws      = (const float*)d_in[3];
    const float* att_src = (const float*)d_in[4];
    const float* att_dst = (const float*)d_in[5];
    const float* biases  = (const float*)d_in[6];
    const float* Wf      = (const float*)d_in[7];
    const float* bf      = (const float*)d_in[8];
    float* y = (float*)d_out;

    char* p = (char*)d_ws;
    auto alloc = [&](size_t bytes) -> void* {
        void* r = (void*)p;
        p += (bytes + 255) & ~(size_t)255;
        return r;
    };
    ushort* xC     = (ushort*)alloc((size_t)(N_NODES + 64) * DIM * 2);  // bf16
    ushort* xA     = (ushort*)alloc((size_t)(N_NODES + 64) * DIM * 2);  // bf16
    uint*   Hb     = (uint*)alloc((size_t)N_NODES * 32 * 4);   // fp8 e4m3, 128 B/row
    ushort* Wfrag  = (ushort*)alloc((size_t)3 * 32 * 64 * 8 * 2);
    uint*  csr     = (uint*)alloc((size_t)E_CAP * 4);          // src|dst<<16 packed
    uint*  cwbuf   = (uint*)alloc((size_t)E_CAP * 4);          // src|bf16(w)<<16
    int*   deg     = (int*)alloc((size_t)N_NODES * 4);
    int*   fillc   = (int*)alloc((size_t)N_NODES * 4);
    int*   row_ptr = (int*)alloc((size_t)(N_NODES + 16) * 4);
    int*   blksum  = (int*)alloc(256 * 4);
    float* s1      = (float*)alloc((size_t)N_NODES * 4);
    float* s2      = (float*)alloc((size_t)(N_NODES + 8) * 4);
    float* pooled  = (float*)alloc((size_t)N_GRAPHS * DIM * 4);

    const int BN = 256;
    const int gN   = (N_NODES + BN - 1) / BN;
    const int gE   = (E_TOT + BN - 1) / BN;
    const int ngroups = N_NODES / 8;                 // 6250, exact
    const int gAGG = (ngroups * 64 + BN - 1) / BN;   // one wave per 8 nodes
    const int nblk = gN;
    const int gCVT = (N_NODES * DIM / 4 + BN - 1) / BN;
    const int gGEMM = (N_NODES + 63) / 64;
    const int gEW  = (NSLOT / 4 + BN - 1) / BN;
    const int gCI  = (NSLOT / 4 + BN - 1) / BN;

    init_kernel<<<gN, BN, 0, stream>>>(deg, fillc, pooled);
    csr_init_kernel<<<gCI, BN, 0, stream>>>(csr);
    x2bf_kernel<<<gCVT, BN, 0, stream>>>(x, xC);
    wprep_kernel<<<(3 * 32 * 64 + BN - 1) / BN, BN, 0, stream>>>(Ws, Wfrag);
    count_kernel<<<gE, BN, 0, stream>>>(ei, deg);
    scan1_kernel<<<nblk, BN, 0, stream>>>(deg, row_ptr, blksum, N_NODES);
    scan2_kernel<<<1, BN, 0, stream>>>(blksum, row_ptr, nblk);
    scan3_kernel<<<gN, BN, 0, stream>>>(row_ptr, blksum, N_NODES);
    fill_kernel<<<gE, BN, 0, stream>>>(ei, row_ptr, fillc, csr);

    const ushort* xin = xC;
    ushort* xout = xA;
    for (int l = 0; l < 3; ++l) {
        const ushort* Wf_l = Wfrag + (size_t)l * 32 * 64 * 8;
        const float* as = att_src + (size_t)l * DIM;
        const float* ad = att_dst + (size_t)l * DIM;
        const float* b  = biases + (size_t)l * DIM;

        gemm_mfma_kernel<<<gGEMM, BN, 0, stream>>>(xin, Wf_l, as, ad, Hb, s1, s2, N_NODES);
        ew_kernel<<<gEW, BN, 0, stream>>>(csr, s1, s2, cwbuf);
        agg_kernel<<<gAGG, BN, 0, stream>>>((const uint2*)Hb, cwbuf, row_ptr, b,
                                            (uint4*)xout, batch, pooled,
                                            (l == 2) ? 1 : 0, ngroups);
        xin = xout;
        xout = (l == 0) ? xC : xA;   // ping-pong: xC free after layer-0 GEMM
    }

    final_kernel<<<(N_GRAPHS * 64 + BN - 1) / BN, BN, 0, stream>>>(pooled, Wf, bf, y);
    (void)ws_size; (void)n_in; (void)in_sizes; (void)out_size;
}

// Round 9
// 399.572 us; speedup vs baseline: 1.4745x; 1.4745x over previous
//
#include <hip/hip_runtime.h>
#include <hip/hip_bf16.h>

#define N_NODES 50000
#define DIM 128
#define N_GRAPHS 64
#define E_RAW 800000
#define E_TOT 850000
#define NSLOT 1000000   // E_TOT + 3*N_NODES: exact upper bound on padded slots
#define E_CAP 1200000   // slack >= 16 words past NSLOT for unconditional chunk loads
#define NEG_SLOPE 0.2f
#define PAD_SENT 0xFFFF0000u   // src field = 0 (safe gather), dst field = 0xFFFF (pad)

typedef unsigned int uint;
typedef unsigned short ushort;
typedef float v2f __attribute__((ext_vector_type(2)));
typedef short bf16x8 __attribute__((ext_vector_type(8)));
typedef float f32x4 __attribute__((ext_vector_type(4)));

// Column permutation pi (storage position -> logical feature), fixed by the
// MFMA C/D fragment layout: pi(p) = (p>>3) + 32*((p>>1)&3) + 16*(p&1)
__device__ __forceinline__ int pi_pos(int p) {
    return (p >> 3) + 32 * ((p >> 1) & 3) + 16 * (p & 1);
}

__device__ __forceinline__ ushort f2bf(float f) {
    uint u = __float_as_uint(f);
    u += 0x7fffu + ((u >> 16) & 1u);      // RNE
    return (ushort)(u >> 16);
}

// ---------- init: counters + pooled only ----------
__global__ void init_kernel(int* deg, int* fillc, float* pooled) {
    int i = blockIdx.x * blockDim.x + threadIdx.x;
    if (i < N_NODES) { deg[i] = 0; fillc[i] = 0; }
    if (i < N_GRAPHS * DIM) pooled[i] = 0.f;
}

// ---------- fill csr[0..NSLOT) with pad sentinel ----------
__global__ void csr_init_kernel(uint* __restrict__ csr) {
    int i = blockIdx.x * blockDim.x + threadIdx.x;
    if (i < NSLOT / 4) ((uint4*)csr)[i] = make_uint4(PAD_SENT, PAD_SENT, PAD_SENT, PAD_SENT);
}

// ---------- layer-0 input fp32 -> bf16 (natural order) ----------
__global__ void x2bf_kernel(const float* __restrict__ x, ushort* __restrict__ xb) {
    int i = blockIdx.x * blockDim.x + threadIdx.x;
    if (i >= N_NODES * DIM / 4) return;
    float4 v = ((const float4*)x)[i];
    ushort4 o;
    o.x = f2bf(v.x); o.y = f2bf(v.y); o.z = f2bf(v.z); o.w = f2bf(v.w);
    ((ushort4*)xb)[i] = o;
}

// ---------- pack W into per-lane MFMA B-fragment layout (bf16) ----------
__global__ void wprep_kernel(const float* __restrict__ Ws, ushort* __restrict__ Wfrag) {
    int t = blockIdx.x * blockDim.x + threadIdx.x;
    if (t >= 3 * 32 * 64) return;
    int l = t >> 11;
    int rem = t & 2047;
    int chunk = rem >> 6, lane = rem & 63;
    int ks = chunk >> 3, nt = chunk & 7;
    int cc = lane & 15, gg = lane >> 4;
    const float* W = Ws + (size_t)l * DIM * DIM;
    ushort o[8];
#pragma unroll
    for (int j = 0; j < 8; ++j) {
        int kp = ks * 32 + gg * 8 + j;
        int kl = (l == 0) ? kp : pi_pos(kp);
        o[j] = f2bf(W[kl * DIM + nt * 16 + cc]);
    }
#pragma unroll
    for (int j = 0; j < 8; ++j) Wfrag[(size_t)t * 8 + j] = o[j];
}

// ---------- CSR build (dst-sorted, segments padded to multiple of 4) ----------
__global__ void count_kernel(const int* __restrict__ ei, int* __restrict__ deg) {
    int e = blockIdx.x * blockDim.x + threadIdx.x;
    if (e >= E_TOT) return;
    int dst = (e < E_RAW) ? ei[E_RAW + e] : (e - E_RAW);
    atomicAdd(&deg[dst], 1);
}

__global__ void scan1_kernel(const int* __restrict__ deg, int* __restrict__ excl,
                             int* __restrict__ blksum, int n) {
    __shared__ int lds[256];
    int t = threadIdx.x;
    int i = blockIdx.x * 256 + t;
    int v = (i < n) ? ((deg[i] + 3) & ~3) : 0;   // pad degree to multiple of 4
    lds[t] = v;
    __syncthreads();
    int incl = v;
    for (int off = 1; off < 256; off <<= 1) {
        int y = (t >= off) ? lds[t - off] : 0;
        __syncthreads();
        incl += y;
        lds[t] = incl;
        __syncthreads();
    }
    if (i < n) excl[i] = incl - v;
    if (t == 255) blksum[blockIdx.x] = incl;
}

__global__ void scan2_kernel(int* __restrict__ blksum, int* __restrict__ row_ptr, int nblk) {
    __shared__ int lds[256];
    int t = threadIdx.x;
    int v = (t < nblk) ? blksum[t] : 0;
    lds[t] = v;
    __syncthreads();
    int incl = v;
    for (int off = 1; off < 256; off <<= 1) {
        int y = (t >= off) ? lds[t - off] : 0;
        __syncthreads();
        incl += y;
        lds[t] = incl;
        __syncthreads();
    }
    if (t < nblk) blksum[t] = incl - v;
    if (t == nblk - 1) row_ptr[N_NODES] = incl;
}

__global__ void scan3_kernel(int* __restrict__ row_ptr, const int* __restrict__ blksum, int n) {
    int i = blockIdx.x * blockDim.x + threadIdx.x;
    if (i < n) row_ptr[i] += blksum[i >> 8];
}

// packed entry: src | (dst<<16). N_NODES < 65536 so both fit.
__global__ void fill_kernel(const int* __restrict__ ei, const int* __restrict__ row_ptr,
                            int* __restrict__ fillc, uint* __restrict__ csr) {
    int e = blockIdx.x * blockDim.x + threadIdx.x;
    if (e >= E_TOT) return;
    int src, dst;
    if (e < E_RAW) { src = ei[e]; dst = ei[E_RAW + e]; }
    else           { src = dst = e - E_RAW; }
    int slot = row_ptr[dst] + atomicAdd(&fillc[dst], 1);
    csr[slot] = (uint)src | ((uint)dst << 16);
}

// ---------- MFMA GEMM + fused attention dots; H packed fp8 e4m3 (pi order) ----
__global__ __launch_bounds__(256) void gemm_mfma_kernel(
    const ushort* __restrict__ Xb, const ushort* __restrict__ Wfrag,
    const float* __restrict__ asrc, const float* __restrict__ adst,
    uint* __restrict__ Hb, float* __restrict__ s1, float* __restrict__ s2, int nrows) {
    int wv = threadIdx.x >> 6;
    int lane = threadIdx.x & 63;
    int c = lane & 15, g = lane >> 4;
    int row0 = blockIdx.x * 64 + wv * 16;

    int arow = row0 + c;
    if (arow >= nrows) arow = nrows - 1;           // tail clamp (writes guarded)
    const ushort* xrow = Xb + (size_t)arow * DIM;

    f32x4 acc[8];
#pragma unroll
    for (int nt = 0; nt < 8; ++nt) acc[nt] = (f32x4)(0.f);

#pragma unroll
    for (int ks = 0; ks < 4; ++ks) {
        bf16x8 afrag = *(const bf16x8*)(xrow + ks * 32 + g * 8);
#pragma unroll
        for (int nt = 0; nt < 8; ++nt) {
            bf16x8 bfrag = *(const bf16x8*)(Wfrag + ((size_t)(ks * 8 + nt) * 64 + lane) * 8);
            acc[nt] = __builtin_amdgcn_mfma_f32_16x16x32_bf16(afrag, bfrag, acc[nt], 0, 0, 0);
        }
    }

    float a1[8], a2[8];
#pragma unroll
    for (int nt = 0; nt < 8; ++nt) { a1[nt] = asrc[c + 16 * nt]; a2[nt] = adst[c + 16 * nt]; }

#pragma unroll
    for (int r = 0; r < 4; ++r) {
        int outrow = row0 + g * 4 + r;
        bool valid = outrow < nrows;
        if (valid) {
            int w0 = __builtin_amdgcn_cvt_pk_fp8_f32(acc[0][r], acc[1][r], 0, false);
            w0     = __builtin_amdgcn_cvt_pk_fp8_f32(acc[2][r], acc[3][r], w0, true);
            int w1 = __builtin_amdgcn_cvt_pk_fp8_f32(acc[4][r], acc[5][r], 0, false);
            w1     = __builtin_amdgcn_cvt_pk_fp8_f32(acc[6][r], acc[7][r], w1, true);
            *(uint2*)&Hb[(size_t)outrow * 32 + c * 2] = make_uint2((uint)w0, (uint)w1);
        }
        float p1 = 0.f, p2 = 0.f;
#pragma unroll
        for (int nt = 0; nt < 8; ++nt) {
            p1 = fmaf(acc[nt][r], a1[nt], p1);
            p2 = fmaf(acc[nt][r], a2[nt], p2);
        }
#pragma unroll
        for (int m = 1; m < 16; m <<= 1) { p1 += __shfl_xor(p1, m); p2 += __shfl_xor(p2, m); }
        if (c == 0 && valid) { s1[outrow] = p1; s2[outrow] = p2; }
    }
}

// ---------- per-edge attention weight, fused into the csr word ----------
// reads csr (src|dst<<16); writes cw = src | bf16(exp(leaky(s1+s2)))<<16.
// pad slots (dst==0xFFFF) -> cw = 0 (src 0, weight +0.0f): safe gather, no-op.
__global__ __launch_bounds__(256) void ew_kernel(
    const uint* __restrict__ csr, const float* __restrict__ s1,
    const float* __restrict__ s2, uint* __restrict__ cw) {
    int i = blockIdx.x * blockDim.x + threadIdx.x;
    if (i >= NSLOT / 4) return;
    uint4 e = ((const uint4*)csr)[i];
    uint ev[4] = {e.x, e.y, e.z, e.w};
    uint ov[4];
#pragma unroll
    for (int j = 0; j < 4; ++j) {
        uint dv = ev[j] >> 16;
        uint sv = ev[j] & 0xFFFFu;
        uint out = 0u;
        if (dv != 0xFFFFu) {
            float al = s1[sv] + s2[dv];
            al = fmaxf(al, NEG_SLOPE * al);     // leaky-relu
            float wv = __expf(al);
            out = sv | ((uint)f2bf(wv) << 16);
        }
        ov[j] = out;
    }
    ((uint4*)cw)[i] = make_uint4(ov[0], ov[1], ov[2], ov[3]);
}

// ---------- weighted gather-aggregate: one wave per FOUR dst nodes ----------
// ROUND-7 loop verbatim (proven 56 us @ 8 nodes/wave): 16 edges/iteration,
// 4 unconditional uint4 cw loads + 4 independent dwordx2 gathers in flight.
// Change: 4 nodes/wave -> 12500 waves (round 7's occupancy was grid-capped
// at 6250 waves / 47%). Segment bounds are WAVE-UNIFORM scalars (round-8
// regression: per-lane-group bounds -> scratch traffic, VALUBusy 2.3%).
// NO readfirstlane, NO runtime-indexed locals (round-3 LDS-demotion trap).
__global__ __launch_bounds__(256) void agg_kernel(
    const uint2* __restrict__ Hb2, const uint* __restrict__ cw,
    const int* __restrict__ row_ptr, const float* __restrict__ bias,
    ushort* __restrict__ Xout, const int* __restrict__ batch,
    float* __restrict__ pooled, int pool_flag, int ngroups) {
    int gw = (blockIdx.x * blockDim.x + threadIdx.x) >> 6;
    int lane = threadIdx.x & 63;
    if (gw >= ngroups) return;
    int node0 = gw * 4;
    int ql = lane & 15;         // uint2 (8-feature) index within fp8 row
    int grp = lane >> 4;        // 0..3: which edge of each 4-edge subchunk

    int4 rpa = *(const int4*)&row_ptr[node0];
    int rp4 = row_ptr[node0 + 4];

    int p0 = 8 * ql + 2 * grp;  // pi-storage position this lane writes (even)
    float2 b2;
    b2.x = bias[pi_pos(p0)];
    b2.y = bias[pi_pos(p0) + 16];

    int ba0 = 0, ba1 = 0, ba2 = 0, ba3 = 0;
    if (pool_flag) {
        int4 bq = *(const int4*)&batch[node0];
        ba0 = bq.x; ba1 = bq.y; ba2 = bq.z; ba3 = bq.w;
    }

    auto seg = [&](int beg, int end, int bk, int node) {
        float a0 = 0.f, a1 = 0.f, a2 = 0.f, a3 = 0.f;
        float a4 = 0.f, a5 = 0.f, a6 = 0.f, a7 = 0.f, ws = 0.f;

        for (int s = beg; s < end; s += 16) {
            uint4 c0 = *(const uint4*)&cw[s];
            uint4 c1 = *(const uint4*)&cw[s + 4];
            uint4 c2 = *(const uint4*)&cw[s + 8];
            uint4 c3 = *(const uint4*)&cw[s + 12];

            uint e0 = (grp == 0) ? c0.x : (grp == 1) ? c0.y : (grp == 2) ? c0.z : c0.w;
            uint e1 = (grp == 0) ? c1.x : (grp == 1) ? c1.y : (grp == 2) ? c1.z : c1.w;
            uint e2 = (grp == 0) ? c2.x : (grp == 1) ? c2.y : (grp == 2) ? c2.z : c2.w;
            uint e3 = (grp == 0) ? c3.x : (grp == 1) ? c3.y : (grp == 2) ? c3.z : c3.w;
            // chunk 0 always valid (end is a multiple of 4); mask chunks 1-3
            e1 = (s + 4 + grp < end) ? e1 : 0u;
            e2 = (s + 8 + grp < end) ? e2 : 0u;
            e3 = (s + 12 + grp < end) ? e3 : 0u;

            // four independent gathers, issued back-to-back
            uint2 h0 = Hb2[(e0 & 0xFFFFu) * 16u + (uint)ql];
            uint2 h1 = Hb2[(e1 & 0xFFFFu) * 16u + (uint)ql];
            uint2 h2 = Hb2[(e2 & 0xFFFFu) * 16u + (uint)ql];
            uint2 h3 = Hb2[(e3 & 0xFFFFu) * 16u + (uint)ql];

            float w0 = __uint_as_float(e0 & 0xFFFF0000u);
            float w1 = __uint_as_float(e1 & 0xFFFF0000u);
            float w2 = __uint_as_float(e2 & 0xFFFF0000u);
            float w3 = __uint_as_float(e3 & 0xFFFF0000u);

            v2f f;
            f = __builtin_amdgcn_cvt_pk_f32_fp8((int)h0.x, false); a0 = fmaf(w0, f.x, a0); a1 = fmaf(w0, f.y, a1);
            f = __builtin_amdgcn_cvt_pk_f32_fp8((int)h0.x, true);  a2 = fmaf(w0, f.x, a2); a3 = fmaf(w0, f.y, a3);
            f = __builtin_amdgcn_cvt_pk_f32_fp8((int)h0.y, false); a4 = fmaf(w0, f.x, a4); a5 = fmaf(w0, f.y, a5);
            f = __builtin_amdgcn_cvt_pk_f32_fp8((int)h0.y, true);  a6 = fmaf(w0, f.x, a6); a7 = fmaf(w0, f.y, a7);
            ws += w0;
            f = __builtin_amdgcn_cvt_pk_f32_fp8((int)h1.x, false); a0 = fmaf(w1, f.x, a0); a1 = fmaf(w1, f.y, a1);
            f = __builtin_amdgcn_cvt_pk_f32_fp8((int)h1.x, true);  a2 = fmaf(w1, f.x, a2); a3 = fmaf(w1, f.y, a3);
            f = __builtin_amdgcn_cvt_pk_f32_fp8((int)h1.y, false); a4 = fmaf(w1, f.x, a4); a5 = fmaf(w1, f.y, a5);
            f = __builtin_amdgcn_cvt_pk_f32_fp8((int)h1.y, true);  a6 = fmaf(w1, f.x, a6); a7 = fmaf(w1, f.y, a7);
            ws += w1;
            f = __builtin_amdgcn_cvt_pk_f32_fp8((int)h2.x, false); a0 = fmaf(w2, f.x, a0); a1 = fmaf(w2, f.y, a1);
            f = __builtin_amdgcn_cvt_pk_f32_fp8((int)h2.x, true);  a2 = fmaf(w2, f.x, a2); a3 = fmaf(w2, f.y, a3);
            f = __builtin_amdgcn_cvt_pk_f32_fp8((int)h2.y, false); a4 = fmaf(w2, f.x, a4); a5 = fmaf(w2, f.y, a5);
            f = __builtin_amdgcn_cvt_pk_f32_fp8((int)h2.y, true);  a6 = fmaf(w2, f.x, a6); a7 = fmaf(w2, f.y, a7);
            ws += w2;
            f = __builtin_amdgcn_cvt_pk_f32_fp8((int)h3.x, false); a0 = fmaf(w3, f.x, a0); a1 = fmaf(w3, f.y, a1);
            f = __builtin_amdgcn_cvt_pk_f32_fp8((int)h3.x, true);  a2 = fmaf(w3, f.x, a2); a3 = fmaf(w3, f.y, a3);
            f = __builtin_amdgcn_cvt_pk_f32_fp8((int)h3.y, false); a4 = fmaf(w3, f.x, a4); a5 = fmaf(w3, f.y, a5);
            f = __builtin_amdgcn_cvt_pk_f32_fp8((int)h3.y, true);  a6 = fmaf(w3, f.x, a6); a7 = fmaf(w3, f.y, a7);
            ws += w3;
        }

        // combine the 4 lane-groups (each held 1/4 of the edges)
        a0 += __shfl_xor(a0, 16); a0 += __shfl_xor(a0, 32);
        a1 += __shfl_xor(a1, 16); a1 += __shfl_xor(a1, 32);
        a2 += __shfl_xor(a2, 16); a2 += __shfl_xor(a2, 32);
        a3 += __shfl_xor(a3, 16); a3 += __shfl_xor(a3, 32);
        a4 += __shfl_xor(a4, 16); a4 += __shfl_xor(a4, 32);
        a5 += __shfl_xor(a5, 16); a5 += __shfl_xor(a5, 32);
        a6 += __shfl_xor(a6, 16); a6 += __shfl_xor(a6, 32);
        a7 += __shfl_xor(a7, 16); a7 += __shfl_xor(a7, 32);
        ws += __shfl_xor(ws, 16); ws += __shfl_xor(ws, 32);

        float inv = 1.f / (ws + 1e-16f);
        float vx = (grp == 0) ? a0 : (grp == 1) ? a2 : (grp == 2) ? a4 : a6;
        float vy = (grp == 0) ? a1 : (grp == 1) ? a3 : (grp == 2) ? a5 : a7;
        vx = fmaxf(fmaf(vx, inv, b2.x), 0.f);
        vy = fmaxf(fmaf(vy, inv, b2.y), 0.f);

        if (pool_flag) {
            atomicAdd(&pooled[bk * DIM + p0], vx);
            atomicAdd(&pooled[bk * DIM + p0 + 1], vy);
        } else {
            ushort2 hb;
            hb.x = f2bf(vx);
            hb.y = f2bf(vy);
            ((ushort2*)Xout)[(size_t)node * 64 + (p0 >> 1)] = hb;
        }
    };

    seg(rpa.x, rpa.y, ba0, node0);
    seg(rpa.y, rpa.z, ba1, node0 + 1);
    seg(rpa.z, rpa.w, ba2, node0 + 2);
    seg(rpa.w, rp4,  ba3, node0 + 3);
}

__global__ void final_kernel(const float* __restrict__ pooled, const float* __restrict__ Wf,
                             const float* __restrict__ bf, float* __restrict__ y) {
    int wid = (blockIdx.x * blockDim.x + threadIdx.x) >> 6;
    int lane = threadIdx.x & 63;
    if (wid >= N_GRAPHS) return;
    float2 p = *(const float2*)&pooled[wid * DIM + 2 * lane];
    int cc = lane >> 2, ii = lane & 3;
    float wx = Wf[cc + 32 * ii];
    float wy = Wf[cc + 32 * ii + 16];
    float v = p.x * wx + p.y * wy;
    for (int off = 32; off; off >>= 1) v += __shfl_down(v, off);
    if (lane == 0) y[wid] = v + bf[0];
}

extern "C" void kernel_launch(void* const* d_in, const int* in_sizes, int n_in,
                              void* d_out, int out_size, void* d_ws, size_t ws_size,
                              hipStream_t stream) {
    const float* x       = (const float*)d_in[0];
    const int*   ei      = (const int*)d_in[1];
    const int*   batch   = (const int*)d_in[2];
    const float* Ws      = (const float*)d_in[3];
    const float* att_src = (const float*)d_in[4];
    const float* att_dst = (const float*)d_in[5];
    const float* biases  = (const float*)d_in[6];
    const float* Wf      = (const float*)d_in[7];
    const float* bf      = (const float*)d_in[8];
    float* y = (float*)d_out;

    char* p = (char*)d_ws;
    auto alloc = [&](size_t bytes) -> void* {
        void* r = (void*)p;
        p += (bytes + 255) & ~(size_t)255;
        return r;
    };
    ushort* xC     = (ushort*)alloc((size_t)(N_NODES + 64) * DIM * 2);  // bf16
    ushort* xA     = (ushort*)alloc((size_t)(N_NODES + 64) * DIM * 2);  // bf16
    uint*   Hb     = (uint*)alloc((size_t)N_NODES * 32 * 4);   // fp8 e4m3, 128 B/row
    ushort* Wfrag  = (ushort*)alloc((size_t)3 * 32 * 64 * 8 * 2);
    uint*  csr     = (uint*)alloc((size_t)E_CAP * 4);          // src|dst<<16 packed
    uint*  cwbuf   = (uint*)alloc((size_t)E_CAP * 4);          // src|bf16(w)<<16
    int*   deg     = (int*)alloc((size_t)N_NODES * 4);
    int*   fillc   = (int*)alloc((size_t)N_NODES * 4);
    int*   row_ptr = (int*)alloc((size_t)(N_NODES + 16) * 4);
    int*   blksum  = (int*)alloc(256 * 4);
    float* s1      = (float*)alloc((size_t)N_NODES * 4);
    float* s2      = (float*)alloc((size_t)(N_NODES + 8) * 4);
    float* pooled  = (float*)alloc((size_t)N_GRAPHS * DIM * 4);

    const int BN = 256;
    const int gN   = (N_NODES + BN - 1) / BN;
    const int gE   = (E_TOT + BN - 1) / BN;
    const int ngroups = N_NODES / 4;                 // 12500, exact
    const int gAGG = (ngroups * 64 + BN - 1) / BN;   // one wave per 4 nodes
    const int nblk = gN;
    const int gCVT = (N_NODES * DIM / 4 + BN - 1) / BN;
    const int gGEMM = (N_NODES + 63) / 64;
    const int gEW  = (NSLOT / 4 + BN - 1) / BN;
    const int gCI  = (NSLOT / 4 + BN - 1) / BN;

    init_kernel<<<gN, BN, 0, stream>>>(deg, fillc, pooled);
    csr_init_kernel<<<gCI, BN, 0, stream>>>(csr);
    x2bf_kernel<<<gCVT, BN, 0, stream>>>(x, xC);
    wprep_kernel<<<(3 * 32 * 64 + BN - 1) / BN, BN, 0, stream>>>(Ws, Wfrag);
    count_kernel<<<gE, BN, 0, stream>>>(ei, deg);
    scan1_kernel<<<nblk, BN, 0, stream>>>(deg, row_ptr, blksum, N_NODES);
    scan2_kernel<<<1, BN, 0, stream>>>(blksum, row_ptr, nblk);
    scan3_kernel<<<gN, BN, 0, stream>>>(row_ptr, blksum, N_NODES);
    fill_kernel<<<gE, BN, 0, stream>>>(ei, row_ptr, fillc, csr);

    const ushort* xin = xC;
    ushort* xout = xA;
    for (int l = 0; l < 3; ++l) {
        const ushort* Wf_l = Wfrag + (size_t)l * 32 * 64 * 8;
        const float* as = att_src + (size_t)l * DIM;
        const float* ad = att_dst + (size_t)l * DIM;
        const float* b  = biases + (size_t)l * DIM;

        gemm_mfma_kernel<<<gGEMM, BN, 0, stream>>>(xin, Wf_l, as, ad, Hb, s1, s2, N_NODES);
        ew_kernel<<<gEW, BN, 0, stream>>>(csr, s1, s2, cwbuf);
        agg_kernel<<<gAGG, BN, 0, stream>>>((const uint2*)Hb, cwbuf, row_ptr, b,
                                            xout, batch, pooled,
                                            (l == 2) ? 1 : 0, ngroups);
        xin = xout;
        xout = (l == 0) ? xC : xA;   // ping-pong: xC free after layer-0 GEMM
    }

    final_kernel<<<(N_GRAPHS * 64 + BN - 1) / BN, BN, 0, stream>>>(pooled, Wf, bf, y);
    (void)ws_size; (void)n_in; (void)in_sizes; (void)out_size;
}

// Round 10
// 348.816 us; speedup vs baseline: 1.6890x; 1.1455x over previous
//
#include <hip/hip_runtime.h>
#include <hip/hip_bf16.h>

#define N_NODES 50000
#define DIM 128
#define N_GRAPHS 64
#define E_RAW 800000
#define E_TOT 850000
#define NSLOT 1000000   // E_TOT + 3*N_NODES: exact upper bound on padded slots
#define E_CAP 1200000   // slack >= 16 words past NSLOT for unconditional chunk loads
#define NEG_SLOPE 0.2f
#define PAD_SENT 0xFFFF0000u   // src field = 0 (safe gather), dst field = 0xFFFF (pad)

typedef unsigned int uint;
typedef unsigned short ushort;
typedef float v2f __attribute__((ext_vector_type(2)));
typedef short bf16x8 __attribute__((ext_vector_type(8)));
typedef float f32x4 __attribute__((ext_vector_type(4)));

// Column permutation pi (storage position -> logical feature), fixed by the
// MFMA C/D fragment layout: pi(p) = (p>>3) + 32*((p>>1)&3) + 16*(p&1)
__device__ __forceinline__ int pi_pos(int p) {
    return (p >> 3) + 32 * ((p >> 1) & 3) + 16 * (p & 1);
}

__device__ __forceinline__ ushort f2bf(float f) {
    uint u = __float_as_uint(f);
    u += 0x7fffu + ((u >> 16) & 1u);      // RNE
    return (ushort)(u >> 16);
}

// ---------- fused prologue: init counters/pooled + csr sentinel + x->bf16 +
// W fragment pack. All writes to DISJOINT buffers; count_kernel (which needs
// deg zeroed) runs in a later dispatch, so no intra-kernel ordering hazard.
__global__ void prep_kernel(const float* __restrict__ x, ushort* __restrict__ xb,
                            const float* __restrict__ Ws, ushort* __restrict__ Wfrag,
                            uint* __restrict__ csr, int* __restrict__ deg,
                            int* __restrict__ fillc, float* __restrict__ pooled) {
    int i = blockIdx.x * blockDim.x + threadIdx.x;
    // x -> bf16 (1.6M items of float4)
    if (i < N_NODES * DIM / 4) {
        float4 v = ((const float4*)x)[i];
        ushort4 o;
        o.x = f2bf(v.x); o.y = f2bf(v.y); o.z = f2bf(v.z); o.w = f2bf(v.w);
        ((ushort4*)xb)[i] = o;
    }
    // csr pad sentinel (250K uint4)
    if (i < NSLOT / 4)
        ((uint4*)csr)[i] = make_uint4(PAD_SENT, PAD_SENT, PAD_SENT, PAD_SENT);
    // counters
    if (i < N_NODES) { deg[i] = 0; fillc[i] = 0; }
    if (i < N_GRAPHS * DIM) pooled[i] = 0.f;
    // W fragment pack (6144 threads)
    if (i < 3 * 32 * 64) {
        int l = i >> 11;
        int rem = i & 2047;
        int chunk = rem >> 6, lane = rem & 63;
        int ks = chunk >> 3, nt = chunk & 7;
        int cc = lane & 15, gg = lane >> 4;
        const float* W = Ws + (size_t)l * DIM * DIM;
        ushort o[8];
#pragma unroll
        for (int j = 0; j < 8; ++j) {
            int kp = ks * 32 + gg * 8 + j;
            int kl = (l == 0) ? kp : pi_pos(kp);
            o[j] = f2bf(W[kl * DIM + nt * 16 + cc]);
        }
#pragma unroll
        for (int j = 0; j < 8; ++j) Wfrag[(size_t)i * 8 + j] = o[j];
    }
}

// ---------- CSR build (dst-sorted, segments padded to multiple of 4) ----------
__global__ void count_kernel(const int* __restrict__ ei, int* __restrict__ deg) {
    int e = blockIdx.x * blockDim.x + threadIdx.x;
    if (e >= E_TOT) return;
    int dst = (e < E_RAW) ? ei[E_RAW + e] : (e - E_RAW);
    atomicAdd(&deg[dst], 1);
}

__global__ void scan1_kernel(const int* __restrict__ deg, int* __restrict__ excl,
                             int* __restrict__ blksum, int n) {
    __shared__ int lds[256];
    int t = threadIdx.x;
    int i = blockIdx.x * 256 + t;
    int v = (i < n) ? ((deg[i] + 3) & ~3) : 0;   // pad degree to multiple of 4
    lds[t] = v;
    __syncthreads();
    int incl = v;
    for (int off = 1; off < 256; off <<= 1) {
        int y = (t >= off) ? lds[t - off] : 0;
        __syncthreads();
        incl += y;
        lds[t] = incl;
        __syncthreads();
    }
    if (i < n) excl[i] = incl - v;
    if (t == 255) blksum[blockIdx.x] = incl;
}

__global__ void scan2_kernel(int* __restrict__ blksum, int* __restrict__ row_ptr, int nblk) {
    __shared__ int lds[256];
    int t = threadIdx.x;
    int v = (t < nblk) ? blksum[t] : 0;
    lds[t] = v;
    __syncthreads();
    int incl = v;
    for (int off = 1; off < 256; off <<= 1) {
        int y = (t >= off) ? lds[t - off] : 0;
        __syncthreads();
        incl += y;
        lds[t] = incl;
        __syncthreads();
    }
    if (t < nblk) blksum[t] = incl - v;
    if (t == nblk - 1) row_ptr[N_NODES] = incl;
}

__global__ void scan3_kernel(int* __restrict__ row_ptr, const int* __restrict__ blksum, int n) {
    int i = blockIdx.x * blockDim.x + threadIdx.x;
    if (i < n) row_ptr[i] += blksum[i >> 8];
}

// packed entry: src | (dst<<16). N_NODES < 65536 so both fit.
__global__ void fill_kernel(const int* __restrict__ ei, const int* __restrict__ row_ptr,
                            int* __restrict__ fillc, uint* __restrict__ csr) {
    int e = blockIdx.x * blockDim.x + threadIdx.x;
    if (e >= E_TOT) return;
    int src, dst;
    if (e < E_RAW) { src = ei[e]; dst = ei[E_RAW + e]; }
    else           { src = dst = e - E_RAW; }
    int slot = row_ptr[dst] + atomicAdd(&fillc[dst], 1);
    csr[slot] = (uint)src | ((uint)dst << 16);
}

// ---------- MFMA GEMM + fused attention dots; H packed fp8 e4m3 (pi order) ----
__global__ __launch_bounds__(256) void gemm_mfma_kernel(
    const ushort* __restrict__ Xb, const ushort* __restrict__ Wfrag,
    const float* __restrict__ asrc, const float* __restrict__ adst,
    uint* __restrict__ Hb, float* __restrict__ s1, float* __restrict__ s2, int nrows) {
    int wv = threadIdx.x >> 6;
    int lane = threadIdx.x & 63;
    int c = lane & 15, g = lane >> 4;
    int row0 = blockIdx.x * 64 + wv * 16;

    int arow = row0 + c;
    if (arow >= nrows) arow = nrows - 1;           // tail clamp (writes guarded)
    const ushort* xrow = Xb + (size_t)arow * DIM;

    f32x4 acc[8];
#pragma unroll
    for (int nt = 0; nt < 8; ++nt) acc[nt] = (f32x4)(0.f);

#pragma unroll
    for (int ks = 0; ks < 4; ++ks) {
        bf16x8 afrag = *(const bf16x8*)(xrow + ks * 32 + g * 8);
#pragma unroll
        for (int nt = 0; nt < 8; ++nt) {
            bf16x8 bfrag = *(const bf16x8*)(Wfrag + ((size_t)(ks * 8 + nt) * 64 + lane) * 8);
            acc[nt] = __builtin_amdgcn_mfma_f32_16x16x32_bf16(afrag, bfrag, acc[nt], 0, 0, 0);
        }
    }

    float a1[8], a2[8];
#pragma unroll
    for (int nt = 0; nt < 8; ++nt) { a1[nt] = asrc[c + 16 * nt]; a2[nt] = adst[c + 16 * nt]; }

#pragma unroll
    for (int r = 0; r < 4; ++r) {
        int outrow = row0 + g * 4 + r;
        bool valid = outrow < nrows;
        if (valid) {
            int w0 = __builtin_amdgcn_cvt_pk_fp8_f32(acc[0][r], acc[1][r], 0, false);
            w0     = __builtin_amdgcn_cvt_pk_fp8_f32(acc[2][r], acc[3][r], w0, true);
            int w1 = __builtin_amdgcn_cvt_pk_fp8_f32(acc[4][r], acc[5][r], 0, false);
            w1     = __builtin_amdgcn_cvt_pk_fp8_f32(acc[6][r], acc[7][r], w1, true);
            *(uint2*)&Hb[(size_t)outrow * 32 + c * 2] = make_uint2((uint)w0, (uint)w1);
        }
        float p1 = 0.f, p2 = 0.f;
#pragma unroll
        for (int nt = 0; nt < 8; ++nt) {
            p1 = fmaf(acc[nt][r], a1[nt], p1);
            p2 = fmaf(acc[nt][r], a2[nt], p2);
        }
#pragma unroll
        for (int m = 1; m < 16; m <<= 1) { p1 += __shfl_xor(p1, m); p2 += __shfl_xor(p2, m); }
        if (c == 0 && valid) { s1[outrow] = p1; s2[outrow] = p2; }
    }
}

// ---------- per-edge attention weight, fused into the csr word ----------
// reads csr (src|dst<<16); writes cw = src | bf16(exp(leaky(s1+s2)))<<16.
// pad slots (dst==0xFFFF) -> cw = 0 (src 0, weight +0.0f): safe gather, no-op.
__global__ __launch_bounds__(256) void ew_kernel(
    const uint* __restrict__ csr, const float* __restrict__ s1,
    const float* __restrict__ s2, uint* __restrict__ cw) {
    int i = blockIdx.x * blockDim.x + threadIdx.x;
    if (i >= NSLOT / 4) return;
    uint4 e = ((const uint4*)csr)[i];
    uint ev[4] = {e.x, e.y, e.z, e.w};
    uint ov[4];
#pragma unroll
    for (int j = 0; j < 4; ++j) {
        uint dv = ev[j] >> 16;
        uint sv = ev[j] & 0xFFFFu;
        uint out = 0u;
        if (dv != 0xFFFFu) {
            float al = s1[sv] + s2[dv];
            al = fmaxf(al, NEG_SLOPE * al);     // leaky-relu
            float wv = __expf(al);
            out = sv | ((uint)f2bf(wv) << 16);
        }
        ov[j] = out;
    }
    ((uint4*)cw)[i] = make_uint4(ov[0], ov[1], ov[2], ov[3]);
}

// ---------- weighted gather-aggregate: one wave per EIGHT dst nodes ----------
// ROUND-7 kernel VERBATIM (measured 56 us): 16 edges/iteration, 4
// unconditional uint4 cw loads + 4 independent dwordx2 gathers in flight.
// 8 nodes/wave proven best 3x (r2/r4/r7 = 67/56/56 vs 4-node r3/r6/r9 =
// 106/88/97) -- agg is random-HBM-fetch bound, not wave-slot bound.
// NO readfirstlane, NO runtime-indexed locals, WAVE-UNIFORM seg bounds.
__global__ __launch_bounds__(256) void agg_kernel(
    const uint2* __restrict__ Hb2, const uint* __restrict__ cw,
    const int* __restrict__ row_ptr, const float* __restrict__ bias,
    ushort* __restrict__ Xout, const int* __restrict__ batch,
    float* __restrict__ pooled, int pool_flag, int ngroups) {
    int gw = (blockIdx.x * blockDim.x + threadIdx.x) >> 6;
    int lane = threadIdx.x & 63;
    if (gw >= ngroups) return;
    int node0 = gw * 8;
    int ql = lane & 15;         // uint2 (8-feature) index within fp8 row
    int grp = lane >> 4;        // 0..3: which edge of each 4-edge subchunk

    int4 rpa = *(const int4*)&row_ptr[node0];
    int4 rpb = *(const int4*)&row_ptr[node0 + 4];
    int rp8 = row_ptr[node0 + 8];

    int p0 = 8 * ql + 2 * grp;  // pi-storage position this lane writes (even)
    float2 b2;
    b2.x = bias[pi_pos(p0)];
    b2.y = bias[pi_pos(p0) + 16];

    int ba0 = 0, ba1 = 0, ba2 = 0, ba3 = 0, ba4 = 0, ba5 = 0, ba6 = 0, ba7 = 0;
    if (pool_flag) {
        int4 bqa = *(const int4*)&batch[node0];
        int4 bqb = *(const int4*)&batch[node0 + 4];
        ba0 = bqa.x; ba1 = bqa.y; ba2 = bqa.z; ba3 = bqa.w;
        ba4 = bqb.x; ba5 = bqb.y; ba6 = bqb.z; ba7 = bqb.w;
    }

    auto seg = [&](int beg, int end, int bk, int node) {
        float a0 = 0.f, a1 = 0.f, a2 = 0.f, a3 = 0.f;
        float a4 = 0.f, a5 = 0.f, a6 = 0.f, a7 = 0.f, ws = 0.f;

        for (int s = beg; s < end; s += 16) {
            uint4 c0 = *(const uint4*)&cw[s];
            uint4 c1 = *(const uint4*)&cw[s + 4];
            uint4 c2 = *(const uint4*)&cw[s + 8];
            uint4 c3 = *(const uint4*)&cw[s + 12];

            uint e0 = (grp == 0) ? c0.x : (grp == 1) ? c0.y : (grp == 2) ? c0.z : c0.w;
            uint e1 = (grp == 0) ? c1.x : (grp == 1) ? c1.y : (grp == 2) ? c1.z : c1.w;
            uint e2 = (grp == 0) ? c2.x : (grp == 1) ? c2.y : (grp == 2) ? c2.z : c2.w;
            uint e3 = (grp == 0) ? c3.x : (grp == 1) ? c3.y : (grp == 2) ? c3.z : c3.w;
            // chunk 0 always valid (end is a multiple of 4); mask chunks 1-3
            e1 = (s + 4 + grp < end) ? e1 : 0u;
            e2 = (s + 8 + grp < end) ? e2 : 0u;
            e3 = (s + 12 + grp < end) ? e3 : 0u;

            // four independent gathers, issued back-to-back
            uint2 h0 = Hb2[(e0 & 0xFFFFu) * 16u + (uint)ql];
            uint2 h1 = Hb2[(e1 & 0xFFFFu) * 16u + (uint)ql];
            uint2 h2 = Hb2[(e2 & 0xFFFFu) * 16u + (uint)ql];
            uint2 h3 = Hb2[(e3 & 0xFFFFu) * 16u + (uint)ql];

            float w0 = __uint_as_float(e0 & 0xFFFF0000u);
            float w1 = __uint_as_float(e1 & 0xFFFF0000u);
            float w2 = __uint_as_float(e2 & 0xFFFF0000u);
            float w3 = __uint_as_float(e3 & 0xFFFF0000u);

            v2f f;
            f = __builtin_amdgcn_cvt_pk_f32_fp8((int)h0.x, false); a0 = fmaf(w0, f.x, a0); a1 = fmaf(w0, f.y, a1);
            f = __builtin_amdgcn_cvt_pk_f32_fp8((int)h0.x, true);  a2 = fmaf(w0, f.x, a2); a3 = fmaf(w0, f.y, a3);
            f = __builtin_amdgcn_cvt_pk_f32_fp8((int)h0.y, false); a4 = fmaf(w0, f.x, a4); a5 = fmaf(w0, f.y, a5);
            f = __builtin_amdgcn_cvt_pk_f32_fp8((int)h0.y, true);  a6 = fmaf(w0, f.x, a6); a7 = fmaf(w0, f.y, a7);
            ws += w0;
            f = __builtin_amdgcn_cvt_pk_f32_fp8((int)h1.x, false); a0 = fmaf(w1, f.x, a0); a1 = fmaf(w1, f.y, a1);
            f = __builtin_amdgcn_cvt_pk_f32_fp8((int)h1.x, true);  a2 = fmaf(w1, f.x, a2); a3 = fmaf(w1, f.y, a3);
            f = __builtin_amdgcn_cvt_pk_f32_fp8((int)h1.y, false); a4 = fmaf(w1, f.x, a4); a5 = fmaf(w1, f.y, a5);
            f = __builtin_amdgcn_cvt_pk_f32_fp8((int)h1.y, true);  a6 = fmaf(w1, f.x, a6); a7 = fmaf(w1, f.y, a7);
            ws += w1;
            f = __builtin_amdgcn_cvt_pk_f32_fp8((int)h2.x, false); a0 = fmaf(w2, f.x, a0); a1 = fmaf(w2, f.y, a1);
            f = __builtin_amdgcn_cvt_pk_f32_fp8((int)h2.x, true);  a2 = fmaf(w2, f.x, a2); a3 = fmaf(w2, f.y, a3);
            f = __builtin_amdgcn_cvt_pk_f32_fp8((int)h2.y, false); a4 = fmaf(w2, f.x, a4); a5 = fmaf(w2, f.y, a5);
            f = __builtin_amdgcn_cvt_pk_f32_fp8((int)h2.y, true);  a6 = fmaf(w2, f.x, a6); a7 = fmaf(w2, f.y, a7);
            ws += w2;
            f = __builtin_amdgcn_cvt_pk_f32_fp8((int)h3.x, false); a0 = fmaf(w3, f.x, a0); a1 = fmaf(w3, f.y, a1);
            f = __builtin_amdgcn_cvt_pk_f32_fp8((int)h3.x, true);  a2 = fmaf(w3, f.x, a2); a3 = fmaf(w3, f.y, a3);
            f = __builtin_amdgcn_cvt_pk_f32_fp8((int)h3.y, false); a4 = fmaf(w3, f.x, a4); a5 = fmaf(w3, f.y, a5);
            f = __builtin_amdgcn_cvt_pk_f32_fp8((int)h3.y, true);  a6 = fmaf(w3, f.x, a6); a7 = fmaf(w3, f.y, a7);
            ws += w3;
        }

        // combine the 4 lane-groups (each held 1/4 of the edges)
        a0 += __shfl_xor(a0, 16); a0 += __shfl_xor(a0, 32);
        a1 += __shfl_xor(a1, 16); a1 += __shfl_xor(a1, 32);
        a2 += __shfl_xor(a2, 16); a2 += __shfl_xor(a2, 32);
        a3 += __shfl_xor(a3, 16); a3 += __shfl_xor(a3, 32);
        a4 += __shfl_xor(a4, 16); a4 += __shfl_xor(a4, 32);
        a5 += __shfl_xor(a5, 16); a5 += __shfl_xor(a5, 32);
        a6 += __shfl_xor(a6, 16); a6 += __shfl_xor(a6, 32);
        a7 += __shfl_xor(a7, 16); a7 += __shfl_xor(a7, 32);
        ws += __shfl_xor(ws, 16); ws += __shfl_xor(ws, 32);

        float inv = 1.f / (ws + 1e-16f);
        float vx = (grp == 0) ? a0 : (grp == 1) ? a2 : (grp == 2) ? a4 : a6;
        float vy = (grp == 0) ? a1 : (grp == 1) ? a3 : (grp == 2) ? a5 : a7;
        vx = fmaxf(fmaf(vx, inv, b2.x), 0.f);
        vy = fmaxf(fmaf(vy, inv, b2.y), 0.f);

        if (pool_flag) {
            atomicAdd(&pooled[bk * DIM + p0], vx);
            atomicAdd(&pooled[bk * DIM + p0 + 1], vy);
        } else {
            ushort2 hb;
            hb.x = f2bf(vx);
            hb.y = f2bf(vy);
            ((ushort2*)Xout)[(size_t)node * 64 + (p0 >> 1)] = hb;
        }
    };

    seg(rpa.x, rpa.y, ba0, node0);
    seg(rpa.y, rpa.z, ba1, node0 + 1);
    seg(rpa.z, rpa.w, ba2, node0 + 2);
    seg(rpa.w, rpb.x, ba3, node0 + 3);
    seg(rpb.x, rpb.y, ba4, node0 + 4);
    seg(rpb.y, rpb.z, ba5, node0 + 5);
    seg(rpb.z, rpb.w, ba6, node0 + 6);
    seg(rpb.w, rp8,  ba7, node0 + 7);
}

__global__ void final_kernel(const float* __restrict__ pooled, const float* __restrict__ Wf,
                             const float* __restrict__ bf, float* __restrict__ y) {
    int wid = (blockIdx.x * blockDim.x + threadIdx.x) >> 6;
    int lane = threadIdx.x & 63;
    if (wid >= N_GRAPHS) return;
    float2 p = *(const float2*)&pooled[wid * DIM + 2 * lane];
    int cc = lane >> 2, ii = lane & 3;
    float wx = Wf[cc + 32 * ii];
    float wy = Wf[cc + 32 * ii + 16];
    float v = p.x * wx + p.y * wy;
    for (int off = 32; off; off >>= 1) v += __shfl_down(v, off);
    if (lane == 0) y[wid] = v + bf[0];
}

extern "C" void kernel_launch(void* const* d_in, const int* in_sizes, int n_in,
                              void* d_out, int out_size, void* d_ws, size_t ws_size,
                              hipStream_t stream) {
    const float* x       = (const float*)d_in[0];
    const int*   ei      = (const int*)d_in[1];
    const int*   batch   = (const int*)d_in[2];
    const float* Ws      = (const float*)d_in[3];
    const float* att_src = (const float*)d_in[4];
    const float* att_dst = (const float*)d_in[5];
    const float* biases  = (const float*)d_in[6];
    const float* Wf      = (const float*)d_in[7];
    const float* bf      = (const float*)d_in[8];
    float* y = (float*)d_out;

    char* p = (char*)d_ws;
    auto alloc = [&](size_t bytes) -> void* {
        void* r = (void*)p;
        p += (bytes + 255) & ~(size_t)255;
        return r;
    };
    ushort* xC     = (ushort*)alloc((size_t)(N_NODES + 64) * DIM * 2);  // bf16
    ushort* xA     = (ushort*)alloc((size_t)(N_NODES + 64) * DIM * 2);  // bf16
    uint*   Hb     = (uint*)alloc((size_t)N_NODES * 32 * 4);   // fp8 e4m3, 128 B/row
    ushort* Wfrag  = (ushort*)alloc((size_t)3 * 32 * 64 * 8 * 2);
    uint*  csr     = (uint*)alloc((size_t)E_CAP * 4);          // src|dst<<16 packed
    uint*  cwbuf   = (uint*)alloc((size_t)E_CAP * 4);          // src|bf16(w)<<16
    int*   deg     = (int*)alloc((size_t)N_NODES * 4);
    int*   fillc   = (int*)alloc((size_t)N_NODES * 4);
    int*   row_ptr = (int*)alloc((size_t)(N_NODES + 16) * 4);
    int*   blksum  = (int*)alloc(256 * 4);
    float* s1      = (float*)alloc((size_t)N_NODES * 4);
    float* s2      = (float*)alloc((size_t)(N_NODES + 8) * 4);
    float* pooled  = (float*)alloc((size_t)N_GRAPHS * DIM * 4);

    const int BN = 256;
    const int gN   = (N_NODES + BN - 1) / BN;
    const int gE   = (E_TOT + BN - 1) / BN;
    const int ngroups = N_NODES / 8;                 // 6250, exact
    const int gAGG = (ngroups * 64 + BN - 1) / BN;   // one wave per 8 nodes
    const int nblk = gN;
    const int gPREP = (N_NODES * DIM / 4 + BN - 1) / BN;   // covers all prep ranges
    const int gGEMM = (N_NODES + 63) / 64;
    const int gEW  = (NSLOT / 4 + BN - 1) / BN;

    prep_kernel<<<gPREP, BN, 0, stream>>>(x, xC, Ws, Wfrag, csr, deg, fillc, pooled);
    count_kernel<<<gE, BN, 0, stream>>>(ei, deg);
    scan1_kernel<<<nblk, BN, 0, stream>>>(deg, row_ptr, blksum, N_NODES);
    scan2_kernel<<<1, BN, 0, stream>>>(blksum, row_ptr, nblk);
    scan3_kernel<<<gN, BN, 0, stream>>>(row_ptr, blksum, N_NODES);
    fill_kernel<<<gE, BN, 0, stream>>>(ei, row_ptr, fillc, csr);

    const ushort* xin = xC;
    ushort* xout = xA;
    for (int l = 0; l < 3; ++l) {
        const ushort* Wf_l = Wfrag + (size_t)l * 32 * 64 * 8;
        const float* as = att_src + (size_t)l * DIM;
        const float* ad = att_dst + (size_t)l * DIM;
        const float* b  = biases + (size_t)l * DIM;

        gemm_mfma_kernel<<<gGEMM, BN, 0, stream>>>(xin, Wf_l, as, ad, Hb, s1, s2, N_NODES);
        ew_kernel<<<gEW, BN, 0, stream>>>(csr, s1, s2, cwbuf);
        agg_kernel<<<gAGG, BN, 0, stream>>>((const uint2*)Hb, cwbuf, row_ptr, b,
                                            xout, batch, pooled,
                                            (l == 2) ? 1 : 0, ngroups);
        xin = xout;
        xout = (l == 0) ? xC : xA;   // ping-pong: xC free after layer-0 GEMM
    }

    final_kernel<<<(N_GRAPHS * 64 + BN - 1) / BN, BN, 0, stream>>>(pooled, Wf, bf, y);
    (void)ws_size; (void)n_in; (void)in_sizes; (void)out_size;
}

// Round 11
// 342.188 us; speedup vs baseline: 1.7217x; 1.0194x over previous
//
#include <hip/hip_runtime.h>
#include <hip/hip_bf16.h>

#define N_NODES 50000
#define DIM 128
#define N_GRAPHS 64
#define E_RAW 800000
#define E_TOT 850000
#define NSLOT 1000000   // E_TOT + 3*N_NODES: exact upper bound on padded slots
#define E_CAP 1200000   // slack >= 16 words past NSLOT for unconditional chunk loads
#define NEG_SLOPE 0.2f
#define PAD_SENT 0xFFFF0000u   // src field = 0 (safe gather), dst field = 0xFFFF (pad)

typedef unsigned int uint;
typedef unsigned short ushort;
typedef float v2f __attribute__((ext_vector_type(2)));
typedef short bf16x8 __attribute__((ext_vector_type(8)));
typedef float f32x4 __attribute__((ext_vector_type(4)));

// Column permutation pi (storage position -> logical feature), fixed by the
// MFMA C/D fragment layout: pi(p) = (p>>3) + 32*((p>>1)&3) + 16*(p&1)
__device__ __forceinline__ int pi_pos(int p) {
    return (p >> 3) + 32 * ((p >> 1) & 3) + 16 * (p & 1);
}

__device__ __forceinline__ ushort f2bf(float f) {
    uint u = __float_as_uint(f);
    u += 0x7fffu + ((u >> 16) & 1u);      // RNE
    return (ushort)(u >> 16);
}

// ---------- fused prologue: init counters/pooled + csr sentinel + x->bf16 +
// W fragment pack. All writes to DISJOINT buffers; count_kernel (which needs
// deg zeroed) runs in a later dispatch, so no intra-kernel ordering hazard.
__global__ void prep_kernel(const float* __restrict__ x, ushort* __restrict__ xb,
                            const float* __restrict__ Ws, ushort* __restrict__ Wfrag,
                            uint* __restrict__ csr, int* __restrict__ deg,
                            int* __restrict__ fillc, float* __restrict__ pooled) {
    int i = blockIdx.x * blockDim.x + threadIdx.x;
    // x -> bf16 (1.6M items of float4)
    if (i < N_NODES * DIM / 4) {
        float4 v = ((const float4*)x)[i];
        ushort4 o;
        o.x = f2bf(v.x); o.y = f2bf(v.y); o.z = f2bf(v.z); o.w = f2bf(v.w);
        ((ushort4*)xb)[i] = o;
    }
    // csr pad sentinel (250K uint4)
    if (i < NSLOT / 4)
        ((uint4*)csr)[i] = make_uint4(PAD_SENT, PAD_SENT, PAD_SENT, PAD_SENT);
    // counters
    if (i < N_NODES) { deg[i] = 0; fillc[i] = 0; }
    if (i < N_GRAPHS * DIM) pooled[i] = 0.f;
    // W fragment pack (6144 threads)
    if (i < 3 * 32 * 64) {
        int l = i >> 11;
        int rem = i & 2047;
        int chunk = rem >> 6, lane = rem & 63;
        int ks = chunk >> 3, nt = chunk & 7;
        int cc = lane & 15, gg = lane >> 4;
        const float* W = Ws + (size_t)l * DIM * DIM;
        ushort o[8];
#pragma unroll
        for (int j = 0; j < 8; ++j) {
            int kp = ks * 32 + gg * 8 + j;
            int kl = (l == 0) ? kp : pi_pos(kp);
            o[j] = f2bf(W[kl * DIM + nt * 16 + cc]);
        }
#pragma unroll
        for (int j = 0; j < 8; ++j) Wfrag[(size_t)i * 8 + j] = o[j];
    }
}

// ---------- CSR build (dst-sorted, segments padded to multiple of 4) ----------
__global__ void count_kernel(const int* __restrict__ ei, int* __restrict__ deg) {
    int e = blockIdx.x * blockDim.x + threadIdx.x;
    if (e >= E_TOT) return;
    int dst = (e < E_RAW) ? ei[E_RAW + e] : (e - E_RAW);
    atomicAdd(&deg[dst], 1);
}

__global__ void scan1_kernel(const int* __restrict__ deg, int* __restrict__ excl,
                             int* __restrict__ blksum, int n) {
    __shared__ int lds[256];
    int t = threadIdx.x;
    int i = blockIdx.x * 256 + t;
    int v = (i < n) ? ((deg[i] + 3) & ~3) : 0;   // pad degree to multiple of 4
    lds[t] = v;
    __syncthreads();
    int incl = v;
    for (int off = 1; off < 256; off <<= 1) {
        int y = (t >= off) ? lds[t - off] : 0;
        __syncthreads();
        incl += y;
        lds[t] = incl;
        __syncthreads();
    }
    if (i < n) excl[i] = incl - v;
    if (t == 255) blksum[blockIdx.x] = incl;
}

__global__ void scan2_kernel(int* __restrict__ blksum, int* __restrict__ row_ptr, int nblk) {
    __shared__ int lds[256];
    int t = threadIdx.x;
    int v = (t < nblk) ? blksum[t] : 0;
    lds[t] = v;
    __syncthreads();
    int incl = v;
    for (int off = 1; off < 256; off <<= 1) {
        int y = (t >= off) ? lds[t - off] : 0;
        __syncthreads();
        incl += y;
        lds[t] = incl;
        __syncthreads();
    }
    if (t < nblk) blksum[t] = incl - v;
    if (t == nblk - 1) row_ptr[N_NODES] = incl;
}

__global__ void scan3_kernel(int* __restrict__ row_ptr, const int* __restrict__ blksum, int n) {
    int i = blockIdx.x * blockDim.x + threadIdx.x;
    if (i < n) row_ptr[i] += blksum[i >> 8];
}

// packed entry: src | (dst<<16). N_NODES < 65536 so both fit.
__global__ void fill_kernel(const int* __restrict__ ei, const int* __restrict__ row_ptr,
                            int* __restrict__ fillc, uint* __restrict__ csr) {
    int e = blockIdx.x * blockDim.x + threadIdx.x;
    if (e >= E_TOT) return;
    int src, dst;
    if (e < E_RAW) { src = ei[e]; dst = ei[E_RAW + e]; }
    else           { src = dst = e - E_RAW; }
    int slot = row_ptr[dst] + atomicAdd(&fillc[dst], 1);
    csr[slot] = (uint)src | ((uint)dst << 16);
}

// ---------- MFMA GEMM + fused attention dots; H packed fp8 e4m3 (pi order) ----
__global__ __launch_bounds__(256) void gemm_mfma_kernel(
    const ushort* __restrict__ Xb, const ushort* __restrict__ Wfrag,
    const float* __restrict__ asrc, const float* __restrict__ adst,
    uint* __restrict__ Hb, float* __restrict__ s1, float* __restrict__ s2, int nrows) {
    int wv = threadIdx.x >> 6;
    int lane = threadIdx.x & 63;
    int c = lane & 15, g = lane >> 4;
    int row0 = blockIdx.x * 64 + wv * 16;

    int arow = row0 + c;
    if (arow >= nrows) arow = nrows - 1;           // tail clamp (writes guarded)
    const ushort* xrow = Xb + (size_t)arow * DIM;

    f32x4 acc[8];
#pragma unroll
    for (int nt = 0; nt < 8; ++nt) acc[nt] = (f32x4)(0.f);

#pragma unroll
    for (int ks = 0; ks < 4; ++ks) {
        bf16x8 afrag = *(const bf16x8*)(xrow + ks * 32 + g * 8);
#pragma unroll
        for (int nt = 0; nt < 8; ++nt) {
            bf16x8 bfrag = *(const bf16x8*)(Wfrag + ((size_t)(ks * 8 + nt) * 64 + lane) * 8);
            acc[nt] = __builtin_amdgcn_mfma_f32_16x16x32_bf16(afrag, bfrag, acc[nt], 0, 0, 0);
        }
    }

    float a1[8], a2[8];
#pragma unroll
    for (int nt = 0; nt < 8; ++nt) { a1[nt] = asrc[c + 16 * nt]; a2[nt] = adst[c + 16 * nt]; }

#pragma unroll
    for (int r = 0; r < 4; ++r) {
        int outrow = row0 + g * 4 + r;
        bool valid = outrow < nrows;
        if (valid) {
            int w0 = __builtin_amdgcn_cvt_pk_fp8_f32(acc[0][r], acc[1][r], 0, false);
            w0     = __builtin_amdgcn_cvt_pk_fp8_f32(acc[2][r], acc[3][r], w0, true);
            int w1 = __builtin_amdgcn_cvt_pk_fp8_f32(acc[4][r], acc[5][r], 0, false);
            w1     = __builtin_amdgcn_cvt_pk_fp8_f32(acc[6][r], acc[7][r], w1, true);
            *(uint2*)&Hb[(size_t)outrow * 32 + c * 2] = make_uint2((uint)w0, (uint)w1);
        }
        float p1 = 0.f, p2 = 0.f;
#pragma unroll
        for (int nt = 0; nt < 8; ++nt) {
            p1 = fmaf(acc[nt][r], a1[nt], p1);
            p2 = fmaf(acc[nt][r], a2[nt], p2);
        }
#pragma unroll
        for (int m = 1; m < 16; m <<= 1) { p1 += __shfl_xor(p1, m); p2 += __shfl_xor(p2, m); }
        if (c == 0 && valid) { s1[outrow] = p1; s2[outrow] = p2; }
    }
}

// ---------- per-edge attention weight, fused into the csr word ----------
// reads csr (src|dst<<16); writes cw = src | bf16(exp(leaky(s1+s2)))<<16.
// pad slots (dst==0xFFFF) -> cw = 0 (src 0, weight +0.0f): safe gather, no-op.
__global__ __launch_bounds__(256) void ew_kernel(
    const uint* __restrict__ csr, const float* __restrict__ s1,
    const float* __restrict__ s2, uint* __restrict__ cw) {
    int i = blockIdx.x * blockDim.x + threadIdx.x;
    if (i >= NSLOT / 4) return;
    uint4 e = ((const uint4*)csr)[i];
    uint ev[4] = {e.x, e.y, e.z, e.w};
    uint ov[4];
#pragma unroll
    for (int j = 0; j < 4; ++j) {
        uint dv = ev[j] >> 16;
        uint sv = ev[j] & 0xFFFFu;
        uint out = 0u;
        if (dv != 0xFFFFu) {
            float al = s1[sv] + s2[dv];
            al = fmaxf(al, NEG_SLOPE * al);     // leaky-relu
            float wv = __expf(al);
            out = sv | ((uint)f2bf(wv) << 16);
        }
        ov[j] = out;
    }
    ((uint4*)cw)[i] = make_uint4(ov[0], ov[1], ov[2], ov[3]);
}

// ---------- weighted gather-aggregate: one wave per EIGHT dst nodes ----------
// ROUND-7 loop (measured 56 us): 16 edges/iteration, 4 unconditional uint4 cw
// loads + 4 independent dwordx2 gathers in flight. 8 nodes/wave proven best 3x.
// NEW: store-coalescing shfl -- lane L takes (vx,vy) of source lane
// S=(L&3)*16+(L>>2) (holds storage positions 2L,2L+1), so the row store is
// lane-linear 4 B/lane over 256 B (was stride-16B permuted: 8x write
// amplification, WRITE_SIZE 50 MB vs 6.4 MB useful).
// NO readfirstlane, NO runtime-indexed locals, WAVE-UNIFORM seg bounds.
__global__ __launch_bounds__(256) void agg_kernel(
    const uint2* __restrict__ Hb2, const uint* __restrict__ cw,
    const int* __restrict__ row_ptr, const float* __restrict__ bias,
    ushort* __restrict__ Xout, const int* __restrict__ batch,
    float* __restrict__ pooled, int pool_flag, int ngroups) {
    int gw = (blockIdx.x * blockDim.x + threadIdx.x) >> 6;
    int lane = threadIdx.x & 63;
    if (gw >= ngroups) return;
    int node0 = gw * 8;
    int ql = lane & 15;         // uint2 (8-feature) index within fp8 row
    int grp = lane >> 4;        // 0..3: which edge of each 4-edge subchunk

    int4 rpa = *(const int4*)&row_ptr[node0];
    int4 rpb = *(const int4*)&row_ptr[node0 + 4];
    int rp8 = row_ptr[node0 + 8];

    int p0 = 8 * ql + 2 * grp;  // pi-storage position this lane accumulates
    float2 b2;
    b2.x = bias[pi_pos(p0)];
    b2.y = bias[pi_pos(p0) + 16];
    int srcl = (lane & 3) * 16 + (lane >> 2);   // store-permutation source lane

    int ba0 = 0, ba1 = 0, ba2 = 0, ba3 = 0, ba4 = 0, ba5 = 0, ba6 = 0, ba7 = 0;
    if (pool_flag) {
        int4 bqa = *(const int4*)&batch[node0];
        int4 bqb = *(const int4*)&batch[node0 + 4];
        ba0 = bqa.x; ba1 = bqa.y; ba2 = bqa.z; ba3 = bqa.w;
        ba4 = bqb.x; ba5 = bqb.y; ba6 = bqb.z; ba7 = bqb.w;
    }

    auto seg = [&](int beg, int end, int bk, int node) {
        float a0 = 0.f, a1 = 0.f, a2 = 0.f, a3 = 0.f;
        float a4 = 0.f, a5 = 0.f, a6 = 0.f, a7 = 0.f, ws = 0.f;

        for (int s = beg; s < end; s += 16) {
            uint4 c0 = *(const uint4*)&cw[s];
            uint4 c1 = *(const uint4*)&cw[s + 4];
            uint4 c2 = *(const uint4*)&cw[s + 8];
            uint4 c3 = *(const uint4*)&cw[s + 12];

            uint e0 = (grp == 0) ? c0.x : (grp == 1) ? c0.y : (grp == 2) ? c0.z : c0.w;
            uint e1 = (grp == 0) ? c1.x : (grp == 1) ? c1.y : (grp == 2) ? c1.z : c1.w;
            uint e2 = (grp == 0) ? c2.x : (grp == 1) ? c2.y : (grp == 2) ? c2.z : c2.w;
            uint e3 = (grp == 0) ? c3.x : (grp == 1) ? c3.y : (grp == 2) ? c3.z : c3.w;
            // chunk 0 always valid (end is a multiple of 4); mask chunks 1-3
            e1 = (s + 4 + grp < end) ? e1 : 0u;
            e2 = (s + 8 + grp < end) ? e2 : 0u;
            e3 = (s + 12 + grp < end) ? e3 : 0u;

            // four independent gathers, issued back-to-back
            uint2 h0 = Hb2[(e0 & 0xFFFFu) * 16u + (uint)ql];
            uint2 h1 = Hb2[(e1 & 0xFFFFu) * 16u + (uint)ql];
            uint2 h2 = Hb2[(e2 & 0xFFFFu) * 16u + (uint)ql];
            uint2 h3 = Hb2[(e3 & 0xFFFFu) * 16u + (uint)ql];

            float w0 = __uint_as_float(e0 & 0xFFFF0000u);
            float w1 = __uint_as_float(e1 & 0xFFFF0000u);
            float w2 = __uint_as_float(e2 & 0xFFFF0000u);
            float w3 = __uint_as_float(e3 & 0xFFFF0000u);

            v2f f;
            f = __builtin_amdgcn_cvt_pk_f32_fp8((int)h0.x, false); a0 = fmaf(w0, f.x, a0); a1 = fmaf(w0, f.y, a1);
            f = __builtin_amdgcn_cvt_pk_f32_fp8((int)h0.x, true);  a2 = fmaf(w0, f.x, a2); a3 = fmaf(w0, f.y, a3);
            f = __builtin_amdgcn_cvt_pk_f32_fp8((int)h0.y, false); a4 = fmaf(w0, f.x, a4); a5 = fmaf(w0, f.y, a5);
            f = __builtin_amdgcn_cvt_pk_f32_fp8((int)h0.y, true);  a6 = fmaf(w0, f.x, a6); a7 = fmaf(w0, f.y, a7);
            ws += w0;
            f = __builtin_amdgcn_cvt_pk_f32_fp8((int)h1.x, false); a0 = fmaf(w1, f.x, a0); a1 = fmaf(w1, f.y, a1);
            f = __builtin_amdgcn_cvt_pk_f32_fp8((int)h1.x, true);  a2 = fmaf(w1, f.x, a2); a3 = fmaf(w1, f.y, a3);
            f = __builtin_amdgcn_cvt_pk_f32_fp8((int)h1.y, false); a4 = fmaf(w1, f.x, a4); a5 = fmaf(w1, f.y, a5);
            f = __builtin_amdgcn_cvt_pk_f32_fp8((int)h1.y, true);  a6 = fmaf(w1, f.x, a6); a7 = fmaf(w1, f.y, a7);
            ws += w1;
            f = __builtin_amdgcn_cvt_pk_f32_fp8((int)h2.x, false); a0 = fmaf(w2, f.x, a0); a1 = fmaf(w2, f.y, a1);
            f = __builtin_amdgcn_cvt_pk_f32_fp8((int)h2.x, true);  a2 = fmaf(w2, f.x, a2); a3 = fmaf(w2, f.y, a3);
            f = __builtin_amdgcn_cvt_pk_f32_fp8((int)h2.y, false); a4 = fmaf(w2, f.x, a4); a5 = fmaf(w2, f.y, a5);
            f = __builtin_amdgcn_cvt_pk_f32_fp8((int)h2.y, true);  a6 = fmaf(w2, f.x, a6); a7 = fmaf(w2, f.y, a7);
            ws += w2;
            f = __builtin_amdgcn_cvt_pk_f32_fp8((int)h3.x, false); a0 = fmaf(w3, f.x, a0); a1 = fmaf(w3, f.y, a1);
            f = __builtin_amdgcn_cvt_pk_f32_fp8((int)h3.x, true);  a2 = fmaf(w3, f.x, a2); a3 = fmaf(w3, f.y, a3);
            f = __builtin_amdgcn_cvt_pk_f32_fp8((int)h3.y, false); a4 = fmaf(w3, f.x, a4); a5 = fmaf(w3, f.y, a5);
            f = __builtin_amdgcn_cvt_pk_f32_fp8((int)h3.y, true);  a6 = fmaf(w3, f.x, a6); a7 = fmaf(w3, f.y, a7);
            ws += w3;
        }

        // combine the 4 lane-groups (each held 1/4 of the edges)
        a0 += __shfl_xor(a0, 16); a0 += __shfl_xor(a0, 32);
        a1 += __shfl_xor(a1, 16); a1 += __shfl_xor(a1, 32);
        a2 += __shfl_xor(a2, 16); a2 += __shfl_xor(a2, 32);
        a3 += __shfl_xor(a3, 16); a3 += __shfl_xor(a3, 32);
        a4 += __shfl_xor(a4, 16); a4 += __shfl_xor(a4, 32);
        a5 += __shfl_xor(a5, 16); a5 += __shfl_xor(a5, 32);
        a6 += __shfl_xor(a6, 16); a6 += __shfl_xor(a6, 32);
        a7 += __shfl_xor(a7, 16); a7 += __shfl_xor(a7, 32);
        ws += __shfl_xor(ws, 16); ws += __shfl_xor(ws, 32);

        float inv = 1.f / (ws + 1e-16f);
        float vx = (grp == 0) ? a0 : (grp == 1) ? a2 : (grp == 2) ? a4 : a6;
        float vy = (grp == 0) ? a1 : (grp == 1) ? a3 : (grp == 2) ? a5 : a7;
        vx = fmaxf(fmaf(vx, inv, b2.x), 0.f);
        vy = fmaxf(fmaf(vy, inv, b2.y), 0.f);

        // lane L takes source lane S's (vx,vy) = storage positions (2L, 2L+1)
        float ox = __shfl(vx, srcl);
        float oy = __shfl(vy, srcl);

        if (pool_flag) {
            atomicAdd(&pooled[bk * DIM + 2 * lane], ox);
            atomicAdd(&pooled[bk * DIM + 2 * lane + 1], oy);
        } else {
            ushort2 hb;
            hb.x = f2bf(ox);
            hb.y = f2bf(oy);
            ((ushort2*)Xout)[(size_t)node * 64 + lane] = hb;   // lane-linear
        }
    };

    seg(rpa.x, rpa.y, ba0, node0);
    seg(rpa.y, rpa.z, ba1, node0 + 1);
    seg(rpa.z, rpa.w, ba2, node0 + 2);
    seg(rpa.w, rpb.x, ba3, node0 + 3);
    seg(rpb.x, rpb.y, ba4, node0 + 4);
    seg(rpb.y, rpb.z, ba5, node0 + 5);
    seg(rpb.z, rpb.w, ba6, node0 + 6);
    seg(rpb.w, rp8,  ba7, node0 + 7);
}

__global__ void final_kernel(const float* __restrict__ pooled, const float* __restrict__ Wf,
                             const float* __restrict__ bf, float* __restrict__ y) {
    int wid = (blockIdx.x * blockDim.x + threadIdx.x) >> 6;
    int lane = threadIdx.x & 63;
    if (wid >= N_GRAPHS) return;
    float2 p = *(const float2*)&pooled[wid * DIM + 2 * lane];
    int cc = lane >> 2, ii = lane & 3;
    float wx = Wf[cc + 32 * ii];
    float wy = Wf[cc + 32 * ii + 16];
    float v = p.x * wx + p.y * wy;
    for (int off = 32; off; off >>= 1) v += __shfl_down(v, off);
    if (lane == 0) y[wid] = v + bf[0];
}

extern "C" void kernel_launch(void* const* d_in, const int* in_sizes, int n_in,
                              void* d_out, int out_size, void* d_ws, size_t ws_size,
                              hipStream_t stream) {
    const float* x       = (const float*)d_in[0];
    const int*   ei      = (const int*)d_in[1];
    const int*   batch   = (const int*)d_in[2];
    const float* Ws      = (const float*)d_in[3];
    const float* att_src = (const float*)d_in[4];
    const float* att_dst = (const float*)d_in[5];
    const float* biases  = (const float*)d_in[6];
    const float* Wf      = (const float*)d_in[7];
    const float* bf      = (const float*)d_in[8];
    float* y = (float*)d_out;

    char* p = (char*)d_ws;
    auto alloc = [&](size_t bytes) -> void* {
        void* r = (void*)p;
        p += (bytes + 255) & ~(size_t)255;
        return r;
    };
    ushort* xC     = (ushort*)alloc((size_t)(N_NODES + 64) * DIM * 2);  // bf16
    ushort* xA     = (ushort*)alloc((size_t)(N_NODES + 64) * DIM * 2);  // bf16
    uint*   Hb     = (uint*)alloc((size_t)N_NODES * 32 * 4);   // fp8 e4m3, 128 B/row
    ushort* Wfrag  = (ushort*)alloc((size_t)3 * 32 * 64 * 8 * 2);
    uint*  csr     = (uint*)alloc((size_t)E_CAP * 4);          // src|dst<<16 packed
    uint*  cwbuf   = (uint*)alloc((size_t)E_CAP * 4);          // src|bf16(w)<<16
    int*   deg     = (int*)alloc((size_t)N_NODES * 4);
    int*   fillc   = (int*)alloc((size_t)N_NODES * 4);
    int*   row_ptr = (int*)alloc((size_t)(N_NODES + 16) * 4);
    int*   blksum  = (int*)alloc(256 * 4);
    float* s1      = (float*)alloc((size_t)N_NODES * 4);
    float* s2      = (float*)alloc((size_t)(N_NODES + 8) * 4);
    float* pooled  = (float*)alloc((size_t)N_GRAPHS * DIM * 4);

    const int BN = 256;
    const int gN   = (N_NODES + BN - 1) / BN;
    const int gE   = (E_TOT + BN - 1) / BN;
    const int ngroups = N_NODES / 8;                 // 6250, exact
    const int gAGG = (ngroups * 64 + BN - 1) / BN;   // one wave per 8 nodes
    const int nblk = gN;
    const int gPREP = (N_NODES * DIM / 4 + BN - 1) / BN;   // covers all prep ranges
    const int gGEMM = (N_NODES + 63) / 64;
    const int gEW  = (NSLOT / 4 + BN - 1) / BN;

    prep_kernel<<<gPREP, BN, 0, stream>>>(x, xC, Ws, Wfrag, csr, deg, fillc, pooled);
    count_kernel<<<gE, BN, 0, stream>>>(ei, deg);
    scan1_kernel<<<nblk, BN, 0, stream>>>(deg, row_ptr, blksum, N_NODES);
    scan2_kernel<<<1, BN, 0, stream>>>(blksum, row_ptr, nblk);
    scan3_kernel<<<gN, BN, 0, stream>>>(row_ptr, blksum, N_NODES);
    fill_kernel<<<gE, BN, 0, stream>>>(ei, row_ptr, fillc, csr);

    const ushort* xin = xC;
    ushort* xout = xA;
    for (int l = 0; l < 3; ++l) {
        const ushort* Wf_l = Wfrag + (size_t)l * 32 * 64 * 8;
        const float* as = att_src + (size_t)l * DIM;
        const float* ad = att_dst + (size_t)l * DIM;
        const float* b  = biases + (size_t)l * DIM;

        gemm_mfma_kernel<<<gGEMM, BN, 0, stream>>>(xin, Wf_l, as, ad, Hb, s1, s2, N_NODES);
        ew_kernel<<<gEW, BN, 0, stream>>>(csr, s1, s2, cwbuf);
        agg_kernel<<<gAGG, BN, 0, stream>>>((const uint2*)Hb, cwbuf, row_ptr, b,
                                            xout, batch, pooled,
                                            (l == 2) ? 1 : 0, ngroups);
        xin = xout;
        xout = (l == 0) ? xC : xA;   // ping-pong: xC free after layer-0 GEMM
    }

    final_kernel<<<(N_GRAPHS * 64 + BN - 1) / BN, BN, 0, stream>>>(pooled, Wf, bf, y);
    (void)ws_size; (void)n_in; (void)in_sizes; (void)out_size;
}